// Round 5
// baseline (271.223 us; speedup 1.0000x reference)
//
#include <hip/hip_runtime.h>
#include <math.h>

#define S_LEN 2048
#define D_DIM 128
#define BHN   32
#define NKT   32   // KV tiles of 64
#define NQT2  16   // Q tiles of 128
#define LOG2E 1.44269504088896340736f

typedef _Float16 f16;
typedef __attribute__((ext_vector_type(4))) _Float16 f16x4;
typedef __attribute__((ext_vector_type(8))) _Float16 f16x8;
typedef __attribute__((ext_vector_type(4))) float    f32x4;

__device__ __forceinline__ void async_cp16(const void* g, void* l) {
  __builtin_amdgcn_global_load_lds(
      (const __attribute__((address_space(1))) unsigned int*)g,
      (__attribute__((address_space(3))) unsigned int*)l,
      16, 0, 0);
}

// ---- fused prepass: one block per (bh, jt) 64-row tile (unchanged; proven).
__global__ __launch_bounds__(256) void prep_kernel(const float* __restrict__ k,
                                                   const float* __restrict__ v,
                                                   f16* __restrict__ kw,
                                                   f16* __restrict__ vtw) {
  __shared__ f16 Vimg[D_DIM * 64];   // 16 KB, final swizzled V^T image

  const int bx = blockIdx.x;
  const int bh = bx >> 5;
  const int jt = bx & 31;
  const int t  = threadIdx.x;

  // ---- K: fp32 -> f16 swizzled tile [r(64)][chunk'(16)][8], chunk' = kd^(r&15)
  {
    const float* kbase = k + ((size_t)bh * S_LEN + jt * 64) * D_DIM;
    f16* ktile = kw + (((size_t)bh * NKT + jt) * 64) * (size_t)D_DIM;
#pragma unroll
    for (int i = 0; i < 4; ++i) {
      int unit = i * 256 + t;
      int kd = unit & 15;
      int r  = unit >> 4;
      const float* src = kbase + r * D_DIM + kd * 8;
      float4 a = *(const float4*)src;
      float4 b = *(const float4*)(src + 4);
      f16x8 vv;
      vv[0]=(f16)a.x; vv[1]=(f16)a.y; vv[2]=(f16)a.z; vv[3]=(f16)a.w;
      vv[4]=(f16)b.x; vv[5]=(f16)b.y; vv[6]=(f16)b.z; vv[7]=(f16)b.w;
      *(f16x8*)(ktile + r * D_DIM + ((kd ^ (r & 15)) * 8)) = vv;
    }
  }

  // ---- V: fp32 -> f16 transposed tile [d(128)][chunk'(8)][8], chunk' = kc^(d&7)
  {
    const int rq = t >> 4;
    const int dg = t & 15;
    const float* base = v + (((size_t)bh * S_LEN + jt * 64 + rq * 4) * D_DIM + dg * 8);
    float rows[4][8];
#pragma unroll
    for (int rr = 0; rr < 4; ++rr) {
      float4 aa = *(const float4*)(base + rr * D_DIM);
      float4 bb = *(const float4*)(base + rr * D_DIM + 4);
      rows[rr][0]=aa.x; rows[rr][1]=aa.y; rows[rr][2]=aa.z; rows[rr][3]=aa.w;
      rows[rr][4]=bb.x; rows[rr][5]=bb.y; rows[rr][6]=bb.z; rows[rr][7]=bb.w;
    }
    const int kc = rq >> 1;
    const int kk = (rq & 1) * 4;
#pragma unroll
    for (int dd0 = 0; dd0 < 8; ++dd0) {
      int dd = (dd0 + dg) & 7;
      int d  = dg * 8 + dd;
      f16x4 p;
      p[0]=(f16)rows[0][dd]; p[1]=(f16)rows[1][dd];
      p[2]=(f16)rows[2][dd]; p[3]=(f16)rows[3][dd];
      *(f16x4*)(Vimg + d * 64 + ((kc ^ dd) * 8) + kk) = p;
    }
    __syncthreads();
    f16* vtile = vtw + ((size_t)bh * NKT + jt) * (size_t)(D_DIM * 64);
#pragma unroll
    for (int i = 0; i < 4; ++i) {
      int idx = i * 256 + t;
      *(f16x8*)(vtile + idx * 8) = *(const f16x8*)(Vimg + idx * 8);
    }
  }
}

// ---- main: flash attention, transposed scores, 2 Q-strips per wave.
// Q-tile = 128 rows; wave w owns rows {s*64 + w*16 + c : s=0,1}. Each K/V
// fragment read from LDS feeds TWO MFMAs (one per strip) -> K/V LDS traffic
// per Q-row halves vs R4; per-iter overhead amortizes over 2x work.
// P rows use stride 68 (bank = 2R+2ch -> balanced; fixes R4's 4-way conflict).
__global__ __launch_bounds__(256) void attn_kernel(const float* __restrict__ q,
                                                   const f16* __restrict__ kw,
                                                   const f16* __restrict__ vtw,
                                                   const float* __restrict__ am,
                                                   const float* __restrict__ hm,
                                                   float* __restrict__ out) {
  __shared__ f16 Klds[64 * 128];    // 16 KB
  __shared__ f16 Vlds[64 * 128];    // 16 KB
  __shared__ f16 Plds[128 * 68];    // 17 KB, rows stride 68

  const int bx   = blockIdx.x;        // 512 blocks
  const int bh   = bx & 31;
  const int slot = bx >> 5;           // 0..15
  const int qi2  = (slot & 1) ? (slot >> 1) : (15 - (slot >> 1)); // heavy/light pairing
  const int b    = bh >> 4;
  const int h    = bh & 15;
  const int t    = threadIdx.x;
  const int w    = t >> 6;
  const int lane = t & 63;
  const int c    = lane & 15;
  const int quad = lane >> 4;
  const int qb   = qi2 * 128;
  const int jmax = 2 * qi2 + 1;

  // Q fragments for both strips (pre-scaled by log2e); B-operand of S^T = K Q^T
  f16x8 qf[2][4];
#pragma unroll
  for (int s = 0; s < 2; ++s) {
    const float* qsrc = q + (((size_t)bh * S_LEN + qb + s * 64 + w * 16 + c) * D_DIM + quad * 8);
#pragma unroll
    for (int ks = 0; ks < 4; ++ks) {
      float4 a  = *(const float4*)(qsrc + ks * 32);
      float4 bb = *(const float4*)(qsrc + ks * 32 + 4);
      f16x8 vv;
      vv[0]=(f16)(a.x*LOG2E);  vv[1]=(f16)(a.y*LOG2E);  vv[2]=(f16)(a.z*LOG2E);  vv[3]=(f16)(a.w*LOG2E);
      vv[4]=(f16)(bb.x*LOG2E); vv[5]=(f16)(bb.y*LOG2E); vv[6]=(f16)(bb.z*LOG2E); vv[7]=(f16)(bb.w*LOG2E);
      qf[s][ks] = vv;
    }
  }

  const float hmv  = hm[h];
  const float* amp = am + (size_t)b * S_LEN;

  f32x4 zero4; zero4[0]=0.f; zero4[1]=0.f; zero4[2]=0.f; zero4[3]=0.f;
  f32x4 oacc[2][8];
#pragma unroll
  for (int s = 0; s < 2; ++s)
#pragma unroll
    for (int dt = 0; dt < 8; ++dt) oacc[s][dt] = zero4;
  float mrow[2] = {-INFINITY, -INFINITY};
  float lrow[2] = {0.f, 0.f};

  const f16* ktiles = kw  + (size_t)bh * NKT * (64 * 128);
  const f16* vtiles = vtw + (size_t)bh * NKT * (64 * 128);

  for (int j = 0; j <= jmax; ++j) {
    const bool s0act = (j <= 2 * qi2);   // strip0 fully masked on the last tile

    __syncthreads();   // (A) all waves done reading previous K/V tiles
    {
      const f16* kg = ktiles + (size_t)j * (64 * 128) + (w * 4) * 512 + lane * 8;
      const f16* vg = vtiles + (size_t)j * (64 * 128) + (w * 4) * 512 + lane * 8;
      f16* kl = Klds + (w * 4) * 512;
      f16* vl = Vlds + (w * 4) * 512;
#pragma unroll
      for (int i = 0; i < 4; ++i) async_cp16(kg + i * 512, kl + i * 512);
#pragma unroll
      for (int i = 0; i < 4; ++i) async_cp16(vg + i * 512, vl + i * 512);
    }
    float amv[4][4];
#pragma unroll
    for (int nt = 0; nt < 4; ++nt) {
      float4 a4 = *(const float4*)(amp + j * 64 + nt * 16 + quad * 4);
      amv[nt][0]=a4.x; amv[nt][1]=a4.y; amv[nt][2]=a4.z; amv[nt][3]=a4.w;
    }
    __syncthreads();   // (B) tiles resident

    // S^T = K (Q*log2e)^T for both strips; each kf read feeds 2 MFMAs
    f32x4 sacc[2][4];
#pragma unroll
    for (int s = 0; s < 2; ++s)
#pragma unroll
      for (int nt = 0; nt < 4; ++nt) sacc[s][nt] = zero4;
#pragma unroll
    for (int ks = 0; ks < 4; ++ks) {
#pragma unroll
      for (int nt = 0; nt < 4; ++nt) {
        const f16x8 kf = *(const f16x8*)(Klds + (nt * 16 + c) * 128 + (((ks * 4 + quad) ^ c) * 8));
        if (s0act)
          sacc[0][nt] = __builtin_amdgcn_mfma_f32_16x16x32_f16(kf, qf[0][ks], sacc[0][nt], 0, 0, 0);
        sacc[1][nt] = __builtin_amdgcn_mfma_f32_16x16x32_f16(kf, qf[1][ks], sacc[1][nt], 0, 0, 0);
      }
    }

    // per-strip: mask (diag tile), softmax, P write
    float alpha[2];
#pragma unroll
    for (int s = 0; s < 2; ++s) {
      if (s == 0 && !s0act) { alpha[0] = 1.f; continue; }
      const bool diag = (j == 2 * qi2 + s);
      if (diag) {
#pragma unroll
        for (int nt = 0; nt < 4; ++nt)
#pragma unroll
          for (int r = 0; r < 4; ++r) {
            int col = nt * 16 + quad * 4 + r;
            if (col > w * 16 + c) sacc[s][nt][r] = -INFINITY;
          }
      }
#pragma unroll
      for (int nt = 0; nt < 4; ++nt)
#pragma unroll
        for (int r = 0; r < 4; ++r) sacc[s][nt][r] = fmaf(amv[nt][r], LOG2E, sacc[s][nt][r]);

      float m16 = sacc[s][0][0];
#pragma unroll
      for (int nt = 0; nt < 4; ++nt)
#pragma unroll
        for (int r = 0; r < 4; ++r) m16 = fmaxf(m16, sacc[s][nt][r]);
      m16 = fmaxf(m16, __shfl_xor(m16, 16));
      m16 = fmaxf(m16, __shfl_xor(m16, 32));
      float mnew = fmaxf(mrow[s], m16);
      alpha[s] = exp2f(mrow[s] - mnew);
      mrow[s] = mnew;

      float psum = 0.f;
#pragma unroll
      for (int nt = 0; nt < 4; ++nt)
#pragma unroll
        for (int r = 0; r < 4; ++r) {
          sacc[s][nt][r] = exp2f(sacc[s][nt][r] - mnew);
          psum += sacc[s][nt][r];
        }
      lrow[s] = lrow[s] * alpha[s] + psum;

      const int R = s * 64 + w * 16 + c;   // P row (q-row in Q-tile)
#pragma unroll
      for (int nt = 0; nt < 4; ++nt) {
        f16x4 p;
        p[0]=(f16)sacc[s][nt][0]; p[1]=(f16)sacc[s][nt][1];
        p[2]=(f16)sacc[s][nt][2]; p[3]=(f16)sacc[s][nt][3];
        int ch = (nt * 4 + quad) ^ ((c & 7) << 1);
        *(f16x4*)(Plds + R * 68 + ch * 4) = p;
      }

      // rescale O accumulator for this strip
      float al[4];
#pragma unroll
      for (int r = 0; r < 4; ++r) al[r] = __shfl(alpha[s], (lane & 48) | (quad * 4 + r));
#pragma unroll
      for (int dt = 0; dt < 8; ++dt)
#pragma unroll
        for (int r = 0; r < 4; ++r) oacc[s][dt][r] *= al[r];
    }

    // O += P V for both strips; each V bf read feeds 2 MFMAs
#pragma unroll
    for (int ks2 = 0; ks2 < 2; ++ks2) {
      const int ch2 = (ks2 * 8 + quad * 2) ^ ((c & 7) << 1);
      f16x8 af0, af1;
      if (s0act) af0 = *(const f16x8*)(Plds + (0 * 64 + w * 16 + c) * 68 + ch2 * 4);
      af1 = *(const f16x8*)(Plds + (1 * 64 + w * 16 + c) * 68 + ch2 * 4);
#pragma unroll
      for (int dt = 0; dt < 8; ++dt) {
        const f16x8 bf = *(const f16x8*)(Vlds + (dt * 16 + c) * 64 + (((ks2 * 4 + quad) ^ (c & 7)) * 8));
        if (s0act)
          oacc[0][dt] = __builtin_amdgcn_mfma_f32_16x16x32_f16(af0, bf, oacc[0][dt], 0, 0, 0);
        oacc[1][dt] = __builtin_amdgcn_mfma_f32_16x16x32_f16(af1, bf, oacc[1][dt], 0, 0, 0);
      }
    }
  }

  // epilogue per strip: reduce l across quad-halves, out = hm * O / l
#pragma unroll
  for (int s = 0; s < 2; ++s) {
    float l = lrow[s];
    l += __shfl_xor(l, 16);
    l += __shfl_xor(l, 32);
    float linv = hmv / l;
    float rinv[4];
#pragma unroll
    for (int r = 0; r < 4; ++r) rinv[r] = __shfl(linv, (lane & 48) | (quad * 4 + r));
    float* obase = out + (((size_t)bh * S_LEN + qb + s * 64 + w * 16) * D_DIM);
#pragma unroll
    for (int dt = 0; dt < 8; ++dt)
#pragma unroll
      for (int r = 0; r < 4; ++r)
        obase[(quad * 4 + r) * D_DIM + dt * 16 + c] = oacc[s][dt][r] * rinv[r];
  }
}

extern "C" void kernel_launch(void* const* d_in, const int* in_sizes, int n_in,
                              void* d_out, int out_size, void* d_ws, size_t ws_size,
                              hipStream_t stream) {
  const float* q  = (const float*)d_in[0];
  const float* k  = (const float*)d_in[1];
  const float* v  = (const float*)d_in[2];
  const float* am = (const float*)d_in[3];
  const float* hm = (const float*)d_in[4];
  float* out = (float*)d_out;

  f16* kw  = (f16*)d_ws;                              // 16.78 MB
  f16* vtw = kw + (size_t)BHN * S_LEN * D_DIM;        // 16.78 MB

  prep_kernel<<<1024, 256, 0, stream>>>(k, v, kw, vtw);
  attn_kernel<<<512, 256, 0, stream>>>(q, kw, vtw, am, hm, out);
}